// Round 12
// baseline (1017.863 us; speedup 1.0000x reference)
//
#include <hip/hip_runtime.h>

#define B_ 16
#define N_ 512
#define F_ 512
#define H_ 16
#define DH_ 32
#define HID_ 2048
#define L_ 6
#define QKV_LD 1536
#define NEGINF -1e9f
#define NEGBF 0xCE6Eu   // bf16(-1e9)
#define ONEBF 0x3F80    // bf16(1.0)

typedef short short8 __attribute__((ext_vector_type(8)));
typedef float f32x4 __attribute__((ext_vector_type(4)));

__device__ __forceinline__ unsigned short f2bf(float f) {
  unsigned int u = __float_as_uint(f);
  unsigned int r = (u + 0x7fff + ((u >> 16) & 1)) >> 16;
  return (unsigned short)r;
}
__device__ __forceinline__ float bf2f(unsigned short v) {
  return __uint_as_float(((unsigned int)v) << 16);
}

// ------------------------------------------------ weight transpose+convert
__global__ __launch_bounds__(256) void tconv4_kernel(
    const float* __restrict__ Wq, const float* __restrict__ Wk,
    const float* __restrict__ Wv, const float* __restrict__ Wo,
    unsigned short* __restrict__ dq, unsigned short* __restrict__ dov)
{
  __shared__ float tile[32][33];
  const int wi = blockIdx.z & 3, l = blockIdx.z >> 2;
  const float* s =
      ((wi == 0) ? Wq : (wi == 1) ? Wk : (wi == 2) ? Wv : Wo) + (size_t)l * F_ * F_;
  unsigned short* d = (wi < 3)
      ? dq + (size_t)l * QKV_LD * F_ + (size_t)wi * 512 * F_
      : dov + (size_t)l * F_ * F_;
  const int n0 = blockIdx.x * 32, k0 = blockIdx.y * 32;
  const int tx = threadIdx.x, ty = threadIdx.y;   // 32x8
#pragma unroll
  for (int i = 0; i < 4; ++i)
    tile[ty + 8 * i][tx] = s[(size_t)(k0 + ty + 8 * i) * F_ + n0 + tx];
  __syncthreads();
#pragma unroll
  for (int i = 0; i < 4; ++i)
    d[(size_t)(n0 + ty + 8 * i) * F_ + k0 + tx] = f2bf(tile[tx][ty + 8 * i]);
}

__global__ __launch_bounds__(256) void tconv_kernel(
    const float* __restrict__ src, unsigned short* __restrict__ dst,
    int K, int N, size_t src_stride_z, size_t dst_stride_z, size_t dst_off)
{
  __shared__ float tile[32][33];
  const int n0 = blockIdx.x * 32, k0 = blockIdx.y * 32;
  const int tx = threadIdx.x, ty = threadIdx.y;   // 32x8
  const float* s = src + blockIdx.z * src_stride_z;
  unsigned short* d = dst + blockIdx.z * dst_stride_z + dst_off;
#pragma unroll
  for (int i = 0; i < 4; ++i)
    tile[ty + 8 * i][tx] = s[(size_t)(k0 + ty + 8 * i) * N + n0 + tx];
  __syncthreads();
#pragma unroll
  for (int i = 0; i < 4; ++i)
    d[(size_t)(n0 + ty + 8 * i) * K + k0 + tx] = f2bf(tile[tx][ty + 8 * i]);
}

__global__ __launch_bounds__(256) void biasqkv_kernel(
    const float* __restrict__ bq, const float* __restrict__ bk,
    const float* __restrict__ bv, float* __restrict__ dst)
{
  int i = blockIdx.x * 256 + threadIdx.x;
  if (i >= L_ * QKV_LD) return;
  int l = i / QKV_LD, j = i % QKV_LD;
  float v = (j < 512) ? bq[l * 512 + j]
          : (j < 1024) ? bk[l * 512 + j - 512] : bv[l * 512 + j - 1024];
  dst[i] = v;
}

// --------------------------------------------- packed dist+mask code table
__global__ __launch_bounds__(256) void packcode_kernel(
    const int* __restrict__ dist, const int* __restrict__ num_nodes,
    unsigned char* __restrict__ code)
{
  int g = blockIdx.x * 256 + threadIdx.x;   // one uchar4 per thread
  int j4 = (g & 127) << 2;
  int bn = g >> 7;
  int b = bn >> 9, i = bn & 511;
  int nn = num_nodes[b];
  int4 d = *(const int4*)(dist + (size_t)bn * N_ + j4);
  bool rinv = i >= nn;
  unsigned char c0 = (j4     >= nn || (rinv && (j4    ) >= 1)) ? 12 : (unsigned char)d.x;
  unsigned char c1 = (j4 + 1 >= nn || (rinv && (j4 + 1) >= 1)) ? 12 : (unsigned char)d.y;
  unsigned char c2 = (j4 + 2 >= nn || (rinv && (j4 + 2) >= 1)) ? 12 : (unsigned char)d.z;
  unsigned char c3 = (j4 + 3 >= nn || (rinv && (j4 + 3) >= 1)) ? 12 : (unsigned char)d.w;
  unsigned int packed = (unsigned int)c0 | ((unsigned int)c1 << 8) |
                        ((unsigned int)c2 << 16) | ((unsigned int)c3 << 24);
  *(unsigned int*)(code + (size_t)bn * N_ + j4) = packed;
}

// ---------------------------------------------------------------- embed (bf16 out only)
__global__ __launch_bounds__(256) void embed_kernel(
    const float* __restrict__ nfeats, const int* __restrict__ degrees,
    const int* __restrict__ num_nodes, const float* __restrict__ din,
    const float* __restrict__ dout, unsigned short* __restrict__ xb)
{
  int g = blockIdx.x * 256 + threadIdx.x;
  int bn = g >> 7;
  int f  = (g & 127) << 2;
  int b  = bn >> 9;
  int n  = bn & 511;
  int nn = num_nodes[b];
  float4 r = {0.f, 0.f, 0.f, 0.f};
  if (n < nn) {
    int deg = degrees[bn];
    deg = deg < 0 ? 0 : (deg > 100 ? 100 : deg);
    float4 a = *(const float4*)(nfeats + (size_t)bn * F_ + f);
    float4 c = *(const float4*)(din + (size_t)deg * F_ + f);
    float4 e = *(const float4*)(dout + (size_t)deg * F_ + f);
    r.x = a.x + c.x + e.x; r.y = a.y + c.y + e.y;
    r.z = a.z + c.z + e.z; r.w = a.w + c.w + e.w;
  }
  unsigned short* xbp = xb + (size_t)bn * F_ + f;
  xbp[0] = f2bf(r.x); xbp[1] = f2bf(r.y); xbp[2] = f2bf(r.z); xbp[3] = f2bf(r.w);
}

// ------------------------------------------------------- bf16 MFMA GEMM (128x128)
// Register-prefetch + ping-pong LDS, XCD row-panel grouping, setprio.
// 64-granular row gate + DEAD-HALF SKIP: in a boundary tile (nnr%128==64)
// the wm=64 waves skip fragment loads/MFMA/epilogue (wave-uniform; staging
// and barriers untouched). Wide-N GEMMs: QKV (epi=2), FFN1 (epi=1).
__global__ __launch_bounds__(256) void mfma_gemm_kernel(
    const unsigned short* __restrict__ A, const unsigned short* __restrict__ Bt,
    const float* __restrict__ bias,
    unsigned short* __restrict__ Cb, unsigned short* __restrict__ vt,
    int K, int Nout, int NC, float scale, int epi,
    const int* __restrict__ num_nodes)
{
  const int bid = blockIdx.x;
  const int xcd = bid & 7, inner = bid >> 3;
  const int ytile = inner % NC, xg = inner / NC;
  const int m0 = ((xg << 3) | xcd) * 128;
  const int n0 = ytile * 128;
  const int nnr = (num_nodes[m0 >> 9] + 63) & ~63;
  if ((m0 & 511) >= nnr) return;

  __shared__ unsigned short SM[4][4096];   // [0..1]=As bufs, [2..3]=Bs bufs (32 KB)

  const int t = threadIdx.x;

  const unsigned short* Ab = A  + (size_t)(m0 + (t >> 2)) * K + (t & 3) * 8;
  const unsigned short* Bb = Bt + (size_t)(n0 + (t >> 2)) * K + (t & 3) * 8;
  const size_t rowskip = (size_t)64 * K;
  const int lo = t * 8;

  const int lane = t & 63, w = t >> 6;
  const int wm = (w & 1) * 64, wn = (w >> 1) * 64;
  const int fr = lane & 15;
  const int fk = (lane >> 4) * 8;
  const bool wlive = ((m0 & 511) + wm) < nnr;   // this wave's 64-row half live?

  short8 ar0, ar1, br0, br1;
#define LOADT(K0)                                        \
  {                                                      \
    ar0 = *(const short8*)(Ab + (K0));                   \
    ar1 = *(const short8*)(Ab + rowskip + (K0));         \
    br0 = *(const short8*)(Bb + (K0));                   \
    br1 = *(const short8*)(Bb + rowskip + (K0));         \
  }
#define STORET(BUF)                                      \
  {                                                      \
    *(short8*)&SM[BUF][lo]            = ar0;             \
    *(short8*)&SM[BUF][lo + 2048]     = ar1;             \
    *(short8*)&SM[2 + (BUF)][lo]        = br0;           \
    *(short8*)&SM[2 + (BUF)][lo + 2048] = br1;           \
  }

  f32x4 acc[4][4];
#pragma unroll
  for (int i = 0; i < 4; ++i)
#pragma unroll
    for (int j = 0; j < 4; ++j) acc[i][j] = (f32x4){0.f, 0.f, 0.f, 0.f};

  LOADT(0)
  STORET(0)
  LOADT(32)

  int buf = 0;
  for (int k0 = 0; k0 < K; k0 += 32, buf ^= 1) {
    __syncthreads();
    if (k0 + 32 < K) {
      STORET(buf ^ 1)
      if (k0 + 64 < K) LOADT(k0 + 64)
    }

    if (wlive) {
      short8 af[4], bf[4];
#pragma unroll
      for (int mi = 0; mi < 4; ++mi)
        af[mi] = *(const short8*)&SM[buf][(wm + mi * 16 + fr) * 32 + fk];
#pragma unroll
      for (int ni = 0; ni < 4; ++ni)
        bf[ni] = *(const short8*)&SM[2 + buf][(wn + ni * 16 + fr) * 32 + fk];
      __builtin_amdgcn_s_setprio(1);
#pragma unroll
      for (int mi = 0; mi < 4; ++mi)
#pragma unroll
        for (int ni = 0; ni < 4; ++ni)
          acc[mi][ni] = __builtin_amdgcn_mfma_f32_16x16x32_bf16(
              af[mi], bf[ni], acc[mi][ni], 0, 0, 0);
      __builtin_amdgcn_s_setprio(0);
    }
  }
#undef LOADT
#undef STORET

  const int er = (lane >> 4) * 4;
  const int ec = lane & 15;

  if (epi == 2 && n0 >= 1024) {
    // ---- V block: restage tile (d=col, j=row) through LDS, coalesced vt out.
    // Dead wave's SMu region holds garbage; those j-rows are >= nnr and never
    // read by attn (jmax = nnr), so the writeout may carry them harmlessly.
    unsigned long long* SMu = (unsigned long long*)&SM[0][0];  // 4096 ulls
    __syncthreads();   // staging reads done everywhere
    if (wlive) {
#pragma unroll
      for (int mi = 0; mi < 4; ++mi) {
#pragma unroll
        for (int ni = 0; ni < 4; ++ni) {
          int d  = wn + ni * 16 + ec;
          int jg = (wm + mi * 16 + er) >> 2;
          float bv = bias[n0 + d];
          unsigned short pk[4];
#pragma unroll
          for (int r = 0; r < 4; ++r) pk[r] = f2bf(acc[mi][ni][r] + bv);
          SMu[d * 32 + (jg ^ (d & 31))] = *(unsigned long long*)pk;
        }
      }
    }
    __syncthreads();
    const int d = t >> 1, half = t & 1;
    const int bb = m0 >> 9, j0t = m0 & 511;
    unsigned short* vrow =
        vt + ((size_t)(bb * 512 + (n0 - 1024) + d)) * 512 + j0t + half * 64;
#pragma unroll
    for (int k = 0; k < 8; ++k) {
      int g0 = half * 16 + 2 * k;
      unsigned long long v2[2];
      v2[0] = SMu[d * 32 + (g0 ^ (d & 31))];
      v2[1] = SMu[d * 32 + ((g0 + 1) ^ (d & 31))];
      *(short8*)(vrow + k * 8) = *(short8*)v2;
    }
    return;
  }

  if (wlive) {
#pragma unroll
    for (int mi = 0; mi < 4; ++mi) {
#pragma unroll
      for (int ni = 0; ni < 4; ++ni) {
        int gm = m0 + wm + mi * 16 + er;
        int gn = n0 + wn + ni * 16 + ec;
        float bv = bias[gn];
#pragma unroll
        for (int r = 0; r < 4; ++r) {
          float v = acc[mi][ni][r] + bv;
          if (epi == 1) v = fmaxf(v, 0.f);
          else if (epi == 2 && gn < 512) v *= scale;
          Cb[(size_t)(gm + r) * Nout + gn] = f2bf(v);
        }
      }
    }
  }
}

// --------------------------------------------- bf16 MFMA GEMM (64x128 tile)
// Narrow-N GEMMs (o-proj, FFN2: 4 col tiles): 64-row tile + 64-granular gate
// culls dead blocks exactly; tiles are always fully live.
__global__ __launch_bounds__(256) void mfma_gemm64_kernel(
    const unsigned short* __restrict__ A, const unsigned short* __restrict__ Bt,
    const float* __restrict__ bias, unsigned short* __restrict__ Cb,
    int K, int Nout, int NC, const int* __restrict__ num_nodes)
{
  const int bid = blockIdx.x;
  const int xcd = bid & 7, inner = bid >> 3;
  const int ytile = inner % NC, xg = inner / NC;
  const int m0 = ((xg << 3) | xcd) * 64;
  const int n0 = ytile * 128;
  {
    const int bb = m0 >> 9;
    const int nnr = (num_nodes[bb] + 63) & ~63;
    if ((m0 & 511) >= nnr) return;
  }

  __shared__ unsigned short As[2][64 * 32];    // 8 KB
  __shared__ unsigned short Bs[2][128 * 32];   // 16 KB

  const int t = threadIdx.x;

  const unsigned short* Ab = A  + (size_t)(m0 + (t >> 2)) * K + (t & 3) * 8;
  const unsigned short* Bb = Bt + (size_t)(n0 + (t >> 2)) * K + (t & 3) * 8;
  const size_t rowskip = (size_t)64 * K;
  const int lo = t * 8;

  const int lane = t & 63, w = t >> 6;
  const int wm = (w & 1) * 32, wn = (w >> 1) * 64;
  const int fr = lane & 15;
  const int fk = (lane >> 4) * 8;

  short8 ar0, br0, br1;
#define LOADT(K0)                                        \
  {                                                      \
    ar0 = *(const short8*)(Ab + (K0));                   \
    br0 = *(const short8*)(Bb + (K0));                   \
    br1 = *(const short8*)(Bb + rowskip + (K0));         \
  }
#define STORET(BUF)                                      \
  {                                                      \
    *(short8*)&As[BUF][lo]        = ar0;                 \
    *(short8*)&Bs[BUF][lo]        = br0;                 \
    *(short8*)&Bs[BUF][lo + 2048] = br1;                 \
  }

  f32x4 acc[2][4];
#pragma unroll
  for (int i = 0; i < 2; ++i)
#pragma unroll
    for (int j = 0; j < 4; ++j) acc[i][j] = (f32x4){0.f, 0.f, 0.f, 0.f};

  LOADT(0)
  STORET(0)
  LOADT(32)

  int buf = 0;
  for (int k0 = 0; k0 < K; k0 += 32, buf ^= 1) {
    __syncthreads();
    if (k0 + 32 < K) {
      STORET(buf ^ 1)
      if (k0 + 64 < K) LOADT(k0 + 64)
    }

    short8 af[2], bf[4];
#pragma unroll
    for (int mi = 0; mi < 2; ++mi)
      af[mi] = *(const short8*)&As[buf][(wm + mi * 16 + fr) * 32 + fk];
#pragma unroll
    for (int ni = 0; ni < 4; ++ni)
      bf[ni] = *(const short8*)&Bs[buf][(wn + ni * 16 + fr) * 32 + fk];
    __builtin_amdgcn_s_setprio(1);
#pragma unroll
    for (int mi = 0; mi < 2; ++mi)
#pragma unroll
      for (int ni = 0; ni < 4; ++ni)
        acc[mi][ni] = __builtin_amdgcn_mfma_f32_16x16x32_bf16(
            af[mi], bf[ni], acc[mi][ni], 0, 0, 0);
    __builtin_amdgcn_s_setprio(0);
  }
#undef LOADT
#undef STORET

  const int er = (lane >> 4) * 4;
  const int ec = lane & 15;
#pragma unroll
  for (int mi = 0; mi < 2; ++mi) {
#pragma unroll
    for (int ni = 0; ni < 4; ++ni) {
      int gm = m0 + wm + mi * 16 + er;
      int gn = n0 + wn + ni * 16 + ec;
      float bv = bias[gn];
#pragma unroll
      for (int r = 0; r < 4; ++r)
        Cb[(size_t)(gm + r) * Nout + gn] = f2bf(acc[mi][ni][r] + bv);
    }
  }
}

// ---------------------------------------------- MFMA flash attention
// 1-D grid: all 16 heads of one (b, i0) share bid%8 -> same XCD (code/K/V
// L2-hot). DEAD-WAVE SKIP: a wave whose 32 q-rows are >= nnr skips dreg
// prefetch, bias expand, QK^T, softmax, PV and the output write; it still
// carries its K/V staging share and all barriers (wave-uniform branch).
__global__ __launch_bounds__(256, 5) void attn_kernel(
    const unsigned short* __restrict__ qkv, const unsigned short* __restrict__ vtb,
    const unsigned char* __restrict__ code, const float* __restrict__ spatial_emb,
    const int* __restrict__ num_nodes, unsigned short* __restrict__ o)
{
  const int bid = blockIdx.x;
  const int xcd = bid & 7;
  const int inner = bid >> 3;       // 0..127
  const int h = inner & 15;
  const int g = (inner >> 4) * 8 + xcd;   // 0..63 = (b, i0-tile) group
  const int b = g >> 2;
  const int i0 = (g & 3) * 128;
  const int nn = num_nodes[b];
  const int nnr = (nn + 63) & ~63;
  if (i0 >= nnr) return;     // dead q-tile (64-granular)
  const int t  = threadIdx.x;
  const int lane = t & 63, w = t >> 6;
  const int q4 = lane >> 4, c = lane & 15;
  const bool wlive = (i0 + w * 32) < nnr;   // this wave's 32 q-rows live?

  __shared__ __align__(16) unsigned short PB[4][32][72];  // 18.4 KB (bias->P; Qs overlay)
  __shared__ short8 Ks[64 * 4];
  __shared__ short8 Vt[32 * 8];
  __shared__ unsigned short sbx[16];

  short8* Qs = (short8*)&PB[0][0][0];

  if (t < 16)
    sbx[t] = (t < 12) ? f2bf(spatial_emb[t * H_ + h]) : (unsigned short)NEGBF;

  {
    int i = t >> 1, half = t & 1;
    const unsigned short* src =
        qkv + (size_t)(b * N_ + i0 + i) * QKV_LD + h * DH_ + half * 16;
    short8 v0 = *(const short8*)src;
    short8 v1 = *(const short8*)(src + 8);
    int sw = (i >> 2) & 3;
    Qs[i * 4 + ((half * 2) ^ sw)]     = v0;
    Qs[i * 4 + ((half * 2 + 1) ^ sw)] = v1;
  }
  __syncthreads();

  const int swz = (c >> 2) & 3;
  short8 Qf[2];
#pragma unroll
  for (int mt = 0; mt < 2; ++mt)
    Qf[mt] = Qs[(w * 32 + mt * 16 + c) * 4 + (q4 ^ swz)];

  short8 ones;
#pragma unroll
  for (int i = 0; i < 8; ++i) ones[i] = (short)ONEBF;

  f32x4 Oa[2][2], Osum[2];
#pragma unroll
  for (int mt = 0; mt < 2; ++mt) {
    Osum[mt] = (f32x4){0.f, 0.f, 0.f, 0.f};
#pragma unroll
    for (int dt = 0; dt < 2; ++dt) Oa[mt][dt] = (f32x4){0.f, 0.f, 0.f, 0.f};
  }

  const int jmax = min(N_, nnr);

  const int kj = t >> 2, kc = t & 3;
  const unsigned short* kbase =
      qkv + (size_t)(b * N_ + kj) * QKV_LD + 512 + h * DH_ + kc * 8;
  const int vd = t >> 3, vjc = t & 7;
  const unsigned short* vbase =
      vtb + ((size_t)(b * 512 + h * DH_ + vd)) * 512 + vjc * 8;
  const unsigned char* cbase = code + (size_t)(b * N_ + i0 + w * 32) * N_;
  const int lc4 = c * 4;

  short8 kreg, vreg;
  unsigned int dreg[8];
#define PREFETCH(J0)                                                           \
  {                                                                            \
    kreg = *(const short8*)(kbase + (size_t)(J0) * QKV_LD);                    \
    vreg = *(const short8*)(vbase + (J0));                                     \
    if (wlive) {                                                               \
      _Pragma("unroll")                                                        \
      for (int it = 0; it < 8; ++it)                                           \
        dreg[it] = *(const unsigned int*)(cbase + (size_t)(it * 4 + q4) * N_ + \
                                          (J0) + lc4);                         \
    }                                                                          \
  }
  PREFETCH(0)

  for (int j0 = 0; j0 < jmax; j0 += 64) {
    __syncthreads();
    Ks[kj * 4 + (kc ^ ((kj >> 2) & 3))] = kreg;
    Vt[vd * 8 + (vjc ^ (vd & 7))] = vreg;
    if (wlive) {
#pragma unroll
      for (int it = 0; it < 8; ++it) {
        unsigned int cw = dreg[it];
        unsigned int e0 = sbx[cw & 15], e1 = sbx[(cw >> 8) & 15];
        unsigned int e2 = sbx[(cw >> 16) & 15], e3 = sbx[cw >> 24];
        unsigned int* pw = (unsigned int*)&PB[w][it * 4 + q4][lc4];
        pw[0] = e0 | (e1 << 16);
        pw[1] = e2 | (e3 << 16);
      }
    }
    __syncthreads();

    if (j0 + 64 < jmax) PREFETCH(j0 + 64)

    if (wlive) {
      f32x4 S[2][4];
#pragma unroll
      for (int nt = 0; nt < 4; ++nt) {
        short8 Kf = Ks[(nt * 16 + c) * 4 + (q4 ^ swz)];
#pragma unroll
        for (int mt = 0; mt < 2; ++mt)
          S[mt][nt] = __builtin_amdgcn_mfma_f32_16x16x32_bf16(
              Qf[mt], Kf, (f32x4){0.f, 0.f, 0.f, 0.f}, 0, 0, 0);
      }

#pragma unroll
      for (int mt = 0; mt < 2; ++mt) {
#pragma unroll
        for (int r = 0; r < 4; ++r) {
          const int row = mt * 16 + q4 * 4 + r;
#pragma unroll
          for (int nt = 0; nt < 4; ++nt) {
            float p = __expf(fminf(S[mt][nt][r] + bf2f(PB[w][row][nt * 16 + c]), 60.f));
            PB[w][row][nt * 16 + c] = f2bf(p);
          }
        }
      }

#pragma unroll
      for (int js = 0; js < 2; ++js) {
        short8 Pa[2], Vf[2];
#pragma unroll
        for (int mt = 0; mt < 2; ++mt)
          Pa[mt] = *(const short8*)&PB[w][mt * 16 + c][js * 32 + q4 * 8];
#pragma unroll
        for (int dt = 0; dt < 2; ++dt) {
          const int d = dt * 16 + c;
          Vf[dt] = Vt[d * 8 + ((js * 4 + q4) ^ (d & 7))];
        }
#pragma unroll
        for (int mt = 0; mt < 2; ++mt) {
#pragma unroll
          for (int dt = 0; dt < 2; ++dt)
            Oa[mt][dt] = __builtin_amdgcn_mfma_f32_16x16x32_bf16(
                Pa[mt], Vf[dt], Oa[mt][dt], 0, 0, 0);
          Osum[mt] = __builtin_amdgcn_mfma_f32_16x16x32_bf16(
              Pa[mt], ones, Osum[mt], 0, 0, 0);
        }
      }
    }
  }
#undef PREFETCH

  if (wlive) {
#pragma unroll
    for (int mt = 0; mt < 2; ++mt)
#pragma unroll
      for (int r = 0; r < 4; ++r) {
        float inv = 1.f / Osum[mt][r];
        int i = i0 + w * 32 + mt * 16 + q4 * 4 + r;
        unsigned short* op = o + (size_t)(b * N_ + i) * F_ + h * DH_;
#pragma unroll
        for (int dt = 0; dt < 2; ++dt)
          op[dt * 16 + c] = f2bf(Oa[mt][dt][r] * inv);
      }
  }
}

// ---------------------------------------------------------------- add + LN
// Wave-per-row: 64 lanes x 8 bf16 = 512 cols; shuffle-only reduce, no LDS,
// no __syncthreads. 4 rows per 256-thread block. xb = LN(xb + t) in place.
__global__ __launch_bounds__(256) void add_ln_kernel(
    unsigned short* __restrict__ xb, const unsigned short* __restrict__ t,
    const float* __restrict__ gam, const float* __restrict__ bet,
    const int* __restrict__ num_nodes)
{
  const int w = threadIdx.x >> 6, lane = threadIdx.x & 63;
  const int row = blockIdx.x * 4 + w;
  {
    int bb = row >> 9;
    int nnr = (num_nodes[bb] + 63) & ~63;
    if ((row & 511) >= nnr) return;   // wave-uniform
  }
  const int c0 = lane * 8;
  const size_t base = (size_t)row * F_ + c0;
  short8 xp = *(const short8*)(xb + base);
  short8 tp = *(const short8*)(t + base);
  float v[8];
#pragma unroll
  for (int j = 0; j < 8; ++j)
    v[j] = bf2f((unsigned short)xp[j]) + bf2f((unsigned short)tp[j]);
  float s = ((v[0] + v[1]) + (v[2] + v[3])) + ((v[4] + v[5]) + (v[6] + v[7]));
#pragma unroll
  for (int off = 32; off > 0; off >>= 1) s += __shfl_xor(s, off, 64);
  float mean = s * (1.f / 512.f);
  float e[8], ss = 0.f;
#pragma unroll
  for (int j = 0; j < 8; ++j) { e[j] = v[j] - mean; ss += e[j] * e[j]; }
#pragma unroll
  for (int off = 32; off > 0; off >>= 1) ss += __shfl_xor(ss, off, 64);
  float rstd = rsqrtf(ss * (1.f / 512.f) + 1e-5f);
  float4 g0 = *(const float4*)(gam + c0);
  float4 g1 = *(const float4*)(gam + c0 + 4);
  float4 b0 = *(const float4*)(bet + c0);
  float4 b1 = *(const float4*)(bet + c0 + 4);
  float g[8] = {g0.x, g0.y, g0.z, g0.w, g1.x, g1.y, g1.z, g1.w};
  float be[8] = {b0.x, b0.y, b0.z, b0.w, b1.x, b1.y, b1.z, b1.w};
  unsigned short o8[8];
#pragma unroll
  for (int j = 0; j < 8; ++j) o8[j] = f2bf(e[j] * rstd * g[j] + be[j]);
  *(short8*)(xb + base) = *(short8*)o8;
}

// ---------------------------------------------------------------- pool (2-stage, bf16 in)
__device__ __forceinline__ float block_reduce_sum(float val, float* sbuf) {
#pragma unroll
  for (int off = 32; off > 0; off >>= 1) val += __shfl_xor(val, off, 64);
  int wid = threadIdx.x >> 6;
  if ((threadIdx.x & 63) == 0) sbuf[wid] = val;
  __syncthreads();
  val = sbuf[0] + sbuf[1] + sbuf[2] + sbuf[3];
  __syncthreads();
  return val;
}

__global__ __launch_bounds__(256) void pool_partial_kernel(
    const unsigned short* __restrict__ xb, const int* __restrict__ num_nodes,
    const float* __restrict__ clf_w, float* __restrict__ part)
{
  __shared__ float sbuf[4];
  int b = blockIdx.x, s = blockIdx.y, t = threadIdx.x;
  int nn = num_nodes[b];
  const unsigned short* xp = xb + (size_t)b * N_ * F_;
  int c0 = t * 2;
  float w0 = clf_w[c0], w1 = clf_w[c0 + 1];
  float a = 0.f;
  for (int n = s; n < nn; n += 32) {
    unsigned int p = *(const unsigned int*)(xp + (size_t)n * F_ + c0);
    a += bf2f((unsigned short)(p & 0xffff)) * w0 + bf2f((unsigned short)(p >> 16)) * w1;
  }
  float tot = block_reduce_sum(a, sbuf);
  if (t == 0) part[b * 32 + s] = tot;
}

__global__ __launch_bounds__(64) void pool_final_kernel(
    const float* __restrict__ part, const int* __restrict__ num_nodes,
    const float* __restrict__ clf_b, float* __restrict__ out)
{
  int b = threadIdx.x;
  if (b >= B_) return;
  float tot = 0.f;
#pragma unroll
  for (int s = 0; s < 32; ++s) tot += part[b * 32 + s];
  float logit = tot / (float)num_nodes[b] + clf_b[0];
  out[b] = 1.f / (1.f + __expf(-logit));
}

// ---------------------------------------------------------------- launch
extern "C" void kernel_launch(void* const* d_in, const int* in_sizes, int n_in,
                              void* d_out, int out_size, void* d_ws, size_t ws_size,
                              hipStream_t stream)
{
  (void)in_sizes; (void)n_in; (void)out_size; (void)ws_size;

  const float* nfeats    = (const float*)d_in[0];
  const int*   degrees   = (const int*)d_in[1];
  const int*   dist_idx  = (const int*)d_in[2];
  const int*   num_nodes = (const int*)d_in[3];
  const float* deg_in    = (const float*)d_in[4];
  const float* deg_out   = (const float*)d_in[5];
  const float* semb      = (const float*)d_in[6];
  const float* Wq = (const float*)d_in[7];  const float* bq = (const float*)d_in[8];
  const float* Wk = (const float*)d_in[9];  const float* bk = (const float*)d_in[10];
  const float* Wv = (const float*)d_in[11]; const float* bv = (const float*)d_in[12];
  const float* Wo = (const float*)d_in[13]; const float* bo = (const float*)d_in[14];
  const float* ln1s = (const float*)d_in[15]; const float* ln1b = (const float*)d_in[16];
  const float* W1 = (const float*)d_in[17]; const float* b1 = (const float*)d_in[18];
  const float* W2 = (const float*)d_in[19]; const float* b2 = (const float*)d_in[20];
  const float* ln2s = (const float*)d_in[21]; const float* ln2b = (const float*)d_in[22];
  const float* clfw = (const float*)d_in[23]; const float* clfb = (const float*)d_in[24];
  float* out = (float*)d_out;

  const int M = B_ * N_;            // 8192
  char* p = (char*)d_ws;
  auto alloc = [&](size_t bytes) { char* r = p; p += (bytes + 255) & ~255ULL; return r; };

  unsigned short* xb    = (unsigned short*)alloc((size_t)M * F_ * 2);     // 8 MB
  char*           R     = alloc((size_t)M * QKV_LD * 4);                  // 50 MB
  unsigned short* ob    = (unsigned short*)alloc((size_t)M * F_ * 2);     // 8 MB
  unsigned short* vtb   = (unsigned short*)alloc((size_t)M * F_ * 2);     // 8 MB V^T
  unsigned short* wQKVt = (unsigned short*)alloc((size_t)L_ * QKV_LD * F_ * 2);
  unsigned short* wOt   = (unsigned short*)alloc((size_t)L_ * F_ * F_ * 2);
  unsigned short* wW1t  = (unsigned short*)alloc((size_t)L_ * HID_ * F_ * 2);
  unsigned short* wW2t  = (unsigned short*)alloc((size_t)L_ * F_ * HID_ * 2);
  float*          bqkv  = (float*)alloc((size_t)L_ * QKV_LD * 4);
  float*          part  = (float*)alloc((size_t)B_ * 32 * 4);
  unsigned char*  code  = (unsigned char*)alloc((size_t)B_ * N_ * N_);    // 4 MB

  unsigned short* qkvb = (unsigned short*)R;                 // bf16 [M][1536]
  unsigned short* tbh  = (unsigned short*)R;                 // bf16 [M][512] (reuse)
  unsigned short* hb   = (unsigned short*)(R + (size_t)M * F_ * 4);  // bf16 [M][2048]

  const float scale = 0.17677669529663687f;  // 1/sqrt(32)

  dim3 tb32(32, 8);
  tconv4_kernel<<<dim3(16, 16, 4 * L_), tb32, 0, stream>>>(
      Wq, Wk, Wv, Wo, wQKVt, wOt);
  tconv_kernel<<<dim3(64, 16, L_), tb32, 0, stream>>>(W1, wW1t, F_, HID_,
      (size_t)F_ * HID_, (size_t)F_ * HID_, 0);
  tconv_kernel<<<dim3(16, 64, L_), tb32, 0, stream>>>(W2, wW2t, HID_, F_,
      (size_t)F_ * HID_, (size_t)F_ * HID_, 0);
  biasqkv_kernel<<<dim3((L_ * QKV_LD + 255) / 256), 256, 0, stream>>>(bq, bk, bv, bqkv);
  packcode_kernel<<<dim3((B_ * N_ * N_) / 4 / 256), 256, 0, stream>>>(
      dist_idx, num_nodes, code);

  embed_kernel<<<dim3((M * F_) / 4 / 256), 256, 0, stream>>>(
      nfeats, degrees, num_nodes, deg_in, deg_out, xb);

  for (int l = 0; l < L_; ++l) {
    const unsigned short* wqkv_l = wQKVt + (size_t)l * QKV_LD * F_;
    const unsigned short* wo_l   = wOt   + (size_t)l * F_ * F_;
    const unsigned short* w1_l   = wW1t  + (size_t)l * HID_ * F_;
    const unsigned short* w2_l   = wW2t  + (size_t)l * F_ * HID_;

    // QKV: 64 row panels x 12 col tiles, 128-row tiles, XCD-grouped
    mfma_gemm_kernel<<<dim3(64 * 12), 256, 0, stream>>>(
        xb, wqkv_l, bqkv + l * QKV_LD, qkvb, vtb, F_, QKV_LD, 12, scale, 2, num_nodes);

    attn_kernel<<<dim3(1024), 256, 0, stream>>>(
        qkvb, vtb, code, semb, num_nodes, ob);

    // o-proj: 128 row panels x 4 col tiles (64-row tiles)
    mfma_gemm64_kernel<<<dim3(128 * 4), 256, 0, stream>>>(
        ob, wo_l, bo + l * F_, tbh, F_, F_, 4, num_nodes);
    add_ln_kernel<<<dim3(M / 4), 256, 0, stream>>>(
        xb, tbh, ln1s + l * F_, ln1b + l * F_, num_nodes);

    // FFN1: 64 row panels x 16 col tiles (128-row tiles)
    mfma_gemm_kernel<<<dim3(64 * 16), 256, 0, stream>>>(
        xb, w1_l, b1 + l * HID_, hb, nullptr, F_, HID_, 16, 1.f, 1, num_nodes);
    // FFN2: 128 row panels x 4 col tiles (64-row tiles), K=2048
    mfma_gemm64_kernel<<<dim3(128 * 4), 256, 0, stream>>>(
        hb, w2_l, b2 + l * F_, tbh, HID_, F_, 4, num_nodes);
    add_ln_kernel<<<dim3(M / 4), 256, 0, stream>>>(
        xb, tbh, ln2s + l * F_, ln2b + l * F_, num_nodes);
  }

  pool_partial_kernel<<<dim3(B_, 32), 256, 0, stream>>>(xb, num_nodes, clfw, part);
  pool_final_kernel<<<dim3(1), 64, 0, stream>>>(part, num_nodes, clfb, out);
}

// Round 14
// 950.233 us; speedup vs baseline: 1.0712x; 1.0712x over previous
//
#include <hip/hip_runtime.h>

#define B_ 16
#define N_ 512
#define F_ 512
#define H_ 16
#define DH_ 32
#define HID_ 2048
#define L_ 6
#define QKV_LD 1536
#define NEGINF -1e9f
#define NEGBF 0xCE6Eu   // bf16(-1e9)
#define ONEBF 0x3F80    // bf16(1.0)

typedef short short8 __attribute__((ext_vector_type(8)));
typedef float f32x4 __attribute__((ext_vector_type(4)));

__device__ __forceinline__ unsigned short f2bf(float f) {
  unsigned int u = __float_as_uint(f);
  unsigned int r = (u + 0x7fff + ((u >> 16) & 1)) >> 16;
  return (unsigned short)r;
}
__device__ __forceinline__ float bf2f(unsigned short v) {
  return __uint_as_float(((unsigned int)v) << 16);
}

// ------------------------------------------------ weight transpose+convert
__global__ __launch_bounds__(256) void tconv4_kernel(
    const float* __restrict__ Wq, const float* __restrict__ Wk,
    const float* __restrict__ Wv, const float* __restrict__ Wo,
    unsigned short* __restrict__ dq, unsigned short* __restrict__ dov)
{
  __shared__ float tile[32][33];
  const int wi = blockIdx.z & 3, l = blockIdx.z >> 2;
  const float* s =
      ((wi == 0) ? Wq : (wi == 1) ? Wk : (wi == 2) ? Wv : Wo) + (size_t)l * F_ * F_;
  unsigned short* d = (wi < 3)
      ? dq + (size_t)l * QKV_LD * F_ + (size_t)wi * 512 * F_
      : dov + (size_t)l * F_ * F_;
  const int n0 = blockIdx.x * 32, k0 = blockIdx.y * 32;
  const int tx = threadIdx.x, ty = threadIdx.y;   // 32x8
#pragma unroll
  for (int i = 0; i < 4; ++i)
    tile[ty + 8 * i][tx] = s[(size_t)(k0 + ty + 8 * i) * F_ + n0 + tx];
  __syncthreads();
#pragma unroll
  for (int i = 0; i < 4; ++i)
    d[(size_t)(n0 + ty + 8 * i) * F_ + k0 + tx] = f2bf(tile[tx][ty + 8 * i]);
}

__global__ __launch_bounds__(256) void tconv_kernel(
    const float* __restrict__ src, unsigned short* __restrict__ dst,
    int K, int N, size_t src_stride_z, size_t dst_stride_z, size_t dst_off)
{
  __shared__ float tile[32][33];
  const int n0 = blockIdx.x * 32, k0 = blockIdx.y * 32;
  const int tx = threadIdx.x, ty = threadIdx.y;   // 32x8
  const float* s = src + blockIdx.z * src_stride_z;
  unsigned short* d = dst + blockIdx.z * dst_stride_z + dst_off;
#pragma unroll
  for (int i = 0; i < 4; ++i)
    tile[ty + 8 * i][tx] = s[(size_t)(k0 + ty + 8 * i) * N + n0 + tx];
  __syncthreads();
#pragma unroll
  for (int i = 0; i < 4; ++i)
    d[(size_t)(n0 + ty + 8 * i) * K + k0 + tx] = f2bf(tile[tx][ty + 8 * i]);
}

__global__ __launch_bounds__(256) void biasqkv_kernel(
    const float* __restrict__ bq, const float* __restrict__ bk,
    const float* __restrict__ bv, float* __restrict__ dst)
{
  int i = blockIdx.x * 256 + threadIdx.x;
  if (i >= L_ * QKV_LD) return;
  int l = i / QKV_LD, j = i % QKV_LD;
  float v = (j < 512) ? bq[l * 512 + j]
          : (j < 1024) ? bk[l * 512 + j - 512] : bv[l * 512 + j - 1024];
  dst[i] = v;
}

// --------------------------------------------- packed dist+mask code table
__global__ __launch_bounds__(256) void packcode_kernel(
    const int* __restrict__ dist, const int* __restrict__ num_nodes,
    unsigned char* __restrict__ code)
{
  int g = blockIdx.x * 256 + threadIdx.x;   // one uchar4 per thread
  int j4 = (g & 127) << 2;
  int bn = g >> 7;
  int b = bn >> 9, i = bn & 511;
  int nn = num_nodes[b];
  int4 d = *(const int4*)(dist + (size_t)bn * N_ + j4);
  bool rinv = i >= nn;
  unsigned char c0 = (j4     >= nn || (rinv && (j4    ) >= 1)) ? 12 : (unsigned char)d.x;
  unsigned char c1 = (j4 + 1 >= nn || (rinv && (j4 + 1) >= 1)) ? 12 : (unsigned char)d.y;
  unsigned char c2 = (j4 + 2 >= nn || (rinv && (j4 + 2) >= 1)) ? 12 : (unsigned char)d.z;
  unsigned char c3 = (j4 + 3 >= nn || (rinv && (j4 + 3) >= 1)) ? 12 : (unsigned char)d.w;
  unsigned int packed = (unsigned int)c0 | ((unsigned int)c1 << 8) |
                        ((unsigned int)c2 << 16) | ((unsigned int)c3 << 24);
  *(unsigned int*)(code + (size_t)bn * N_ + j4) = packed;
}

// ---------------------------------------------------------------- embed (bf16 out only)
__global__ __launch_bounds__(256) void embed_kernel(
    const float* __restrict__ nfeats, const int* __restrict__ degrees,
    const int* __restrict__ num_nodes, const float* __restrict__ din,
    const float* __restrict__ dout, unsigned short* __restrict__ xb)
{
  int g = blockIdx.x * 256 + threadIdx.x;
  int bn = g >> 7;
  int f  = (g & 127) << 2;
  int b  = bn >> 9;
  int n  = bn & 511;
  int nn = num_nodes[b];
  float4 r = {0.f, 0.f, 0.f, 0.f};
  if (n < nn) {
    int deg = degrees[bn];
    deg = deg < 0 ? 0 : (deg > 100 ? 100 : deg);
    float4 a = *(const float4*)(nfeats + (size_t)bn * F_ + f);
    float4 c = *(const float4*)(din + (size_t)deg * F_ + f);
    float4 e = *(const float4*)(dout + (size_t)deg * F_ + f);
    r.x = a.x + c.x + e.x; r.y = a.y + c.y + e.y;
    r.z = a.z + c.z + e.z; r.w = a.w + c.w + e.w;
  }
  unsigned short* xbp = xb + (size_t)bn * F_ + f;
  xbp[0] = f2bf(r.x); xbp[1] = f2bf(r.y); xbp[2] = f2bf(r.z); xbp[3] = f2bf(r.w);
}

// ------------------------------------------------------- bf16 MFMA GEMM (128x128)
// Register-prefetch + ping-pong LDS, XCD row-panel grouping, setprio.
// 64-granular row gate. Wide-N GEMMs (QKV epi=2, FFN1 epi=1): the 128-row
// tile amortizes B staging across fewer blocks (R10 showed 64-row here loses;
// R12 showed conditional dead-half skip breaks pipelining -> unconditional).
__global__ __launch_bounds__(256) void mfma_gemm_kernel(
    const unsigned short* __restrict__ A, const unsigned short* __restrict__ Bt,
    const float* __restrict__ bias,
    unsigned short* __restrict__ Cb, unsigned short* __restrict__ vt,
    int K, int Nout, int NC, float scale, int epi,
    const int* __restrict__ num_nodes)
{
  const int bid = blockIdx.x;
  const int xcd = bid & 7, inner = bid >> 3;
  const int ytile = inner % NC, xg = inner / NC;
  const int m0 = ((xg << 3) | xcd) * 128;
  const int n0 = ytile * 128;
  {
    const int bb = m0 >> 9;
    const int nnr = (num_nodes[bb] + 63) & ~63;
    if ((m0 & 511) >= nnr) return;
  }

  __shared__ unsigned short SM[4][4096];   // [0..1]=As bufs, [2..3]=Bs bufs (32 KB)

  const int t = threadIdx.x;

  const unsigned short* Ab = A  + (size_t)(m0 + (t >> 2)) * K + (t & 3) * 8;
  const unsigned short* Bb = Bt + (size_t)(n0 + (t >> 2)) * K + (t & 3) * 8;
  const size_t rowskip = (size_t)64 * K;
  const int lo = t * 8;

  const int lane = t & 63, w = t >> 6;
  const int wm = (w & 1) * 64, wn = (w >> 1) * 64;
  const int fr = lane & 15;
  const int fk = (lane >> 4) * 8;

  short8 ar0, ar1, br0, br1;
#define LOADT(K0)                                        \
  {                                                      \
    ar0 = *(const short8*)(Ab + (K0));                   \
    ar1 = *(const short8*)(Ab + rowskip + (K0));         \
    br0 = *(const short8*)(Bb + (K0));                   \
    br1 = *(const short8*)(Bb + rowskip + (K0));         \
  }
#define STORET(BUF)                                      \
  {                                                      \
    *(short8*)&SM[BUF][lo]            = ar0;             \
    *(short8*)&SM[BUF][lo + 2048]     = ar1;             \
    *(short8*)&SM[2 + (BUF)][lo]        = br0;           \
    *(short8*)&SM[2 + (BUF)][lo + 2048] = br1;           \
  }

  f32x4 acc[4][4];
#pragma unroll
  for (int i = 0; i < 4; ++i)
#pragma unroll
    for (int j = 0; j < 4; ++j) acc[i][j] = (f32x4){0.f, 0.f, 0.f, 0.f};

  LOADT(0)
  STORET(0)
  LOADT(32)

  int buf = 0;
  for (int k0 = 0; k0 < K; k0 += 32, buf ^= 1) {
    __syncthreads();
    if (k0 + 32 < K) {
      STORET(buf ^ 1)
      if (k0 + 64 < K) LOADT(k0 + 64)
    }

    short8 af[4], bf[4];
#pragma unroll
    for (int mi = 0; mi < 4; ++mi)
      af[mi] = *(const short8*)&SM[buf][(wm + mi * 16 + fr) * 32 + fk];
#pragma unroll
    for (int ni = 0; ni < 4; ++ni)
      bf[ni] = *(const short8*)&SM[2 + buf][(wn + ni * 16 + fr) * 32 + fk];
    __builtin_amdgcn_s_setprio(1);
#pragma unroll
    for (int mi = 0; mi < 4; ++mi)
#pragma unroll
      for (int ni = 0; ni < 4; ++ni)
        acc[mi][ni] = __builtin_amdgcn_mfma_f32_16x16x32_bf16(
            af[mi], bf[ni], acc[mi][ni], 0, 0, 0);
    __builtin_amdgcn_s_setprio(0);
  }
#undef LOADT
#undef STORET

  const int er = (lane >> 4) * 4;
  const int ec = lane & 15;

  if (epi == 2 && n0 >= 1024) {
    // ---- V block: restage tile (d=col, j=row) through LDS, coalesced vt out
    unsigned long long* SMu = (unsigned long long*)&SM[0][0];  // 4096 ulls
    __syncthreads();   // staging reads done everywhere
#pragma unroll
    for (int mi = 0; mi < 4; ++mi) {
#pragma unroll
      for (int ni = 0; ni < 4; ++ni) {
        int d  = wn + ni * 16 + ec;
        int jg = (wm + mi * 16 + er) >> 2;
        float bv = bias[n0 + d];
        unsigned short pk[4];
#pragma unroll
        for (int r = 0; r < 4; ++r) pk[r] = f2bf(acc[mi][ni][r] + bv);
        SMu[d * 32 + (jg ^ (d & 31))] = *(unsigned long long*)pk;
      }
    }
    __syncthreads();
    const int d = t >> 1, half = t & 1;
    const int bb = m0 >> 9, j0t = m0 & 511;
    unsigned short* vrow =
        vt + ((size_t)(bb * 512 + (n0 - 1024) + d)) * 512 + j0t + half * 64;
#pragma unroll
    for (int k = 0; k < 8; ++k) {
      int g0 = half * 16 + 2 * k;
      unsigned long long v2[2];
      v2[0] = SMu[d * 32 + (g0 ^ (d & 31))];
      v2[1] = SMu[d * 32 + ((g0 + 1) ^ (d & 31))];
      *(short8*)(vrow + k * 8) = *(short8*)v2;
    }
    return;
  }

#pragma unroll
  for (int mi = 0; mi < 4; ++mi) {
#pragma unroll
    for (int ni = 0; ni < 4; ++ni) {
      int gm = m0 + wm + mi * 16 + er;
      int gn = n0 + wn + ni * 16 + ec;
      float bv = bias[gn];
#pragma unroll
      for (int r = 0; r < 4; ++r) {
        float v = acc[mi][ni][r] + bv;
        if (epi == 1) v = fmaxf(v, 0.f);
        else if (epi == 2 && gn < 512) v *= scale;
        Cb[(size_t)(gm + r) * Nout + gn] = f2bf(v);
      }
    }
  }
}

// --------------------------------------------- bf16 MFMA GEMM (64x128 tile)
// Narrow-N GEMMs (o-proj, FFN2: 4 col tiles): 64-row tile + 64-granular gate
// culls ~10% dead blocks; B-amortization loss negligible at NC=4.
__global__ __launch_bounds__(256) void mfma_gemm64_kernel(
    const unsigned short* __restrict__ A, const unsigned short* __restrict__ Bt,
    const float* __restrict__ bias, unsigned short* __restrict__ Cb,
    int K, int Nout, int NC, const int* __restrict__ num_nodes)
{
  const int bid = blockIdx.x;
  const int xcd = bid & 7, inner = bid >> 3;
  const int ytile = inner % NC, xg = inner / NC;
  const int m0 = ((xg << 3) | xcd) * 64;
  const int n0 = ytile * 128;
  {
    const int bb = m0 >> 9;
    const int nnr = (num_nodes[bb] + 63) & ~63;
    if ((m0 & 511) >= nnr) return;
  }

  __shared__ unsigned short As[2][64 * 32];    // 8 KB
  __shared__ unsigned short Bs[2][128 * 32];   // 16 KB

  const int t = threadIdx.x;

  const unsigned short* Ab = A  + (size_t)(m0 + (t >> 2)) * K + (t & 3) * 8;
  const unsigned short* Bb = Bt + (size_t)(n0 + (t >> 2)) * K + (t & 3) * 8;
  const size_t rowskip = (size_t)64 * K;
  const int lo = t * 8;

  const int lane = t & 63, w = t >> 6;
  const int wm = (w & 1) * 32, wn = (w >> 1) * 64;
  const int fr = lane & 15;
  const int fk = (lane >> 4) * 8;

  short8 ar0, br0, br1;
#define LOADT(K0)                                        \
  {                                                      \
    ar0 = *(const short8*)(Ab + (K0));                   \
    br0 = *(const short8*)(Bb + (K0));                   \
    br1 = *(const short8*)(Bb + rowskip + (K0));         \
  }
#define STORET(BUF)                                      \
  {                                                      \
    *(short8*)&As[BUF][lo]        = ar0;                 \
    *(short8*)&Bs[BUF][lo]        = br0;                 \
    *(short8*)&Bs[BUF][lo + 2048] = br1;                 \
  }

  f32x4 acc[2][4];
#pragma unroll
  for (int i = 0; i < 2; ++i)
#pragma unroll
    for (int j = 0; j < 4; ++j) acc[i][j] = (f32x4){0.f, 0.f, 0.f, 0.f};

  LOADT(0)
  STORET(0)
  LOADT(32)

  int buf = 0;
  for (int k0 = 0; k0 < K; k0 += 32, buf ^= 1) {
    __syncthreads();
    if (k0 + 32 < K) {
      STORET(buf ^ 1)
      if (k0 + 64 < K) LOADT(k0 + 64)
    }

    short8 af[2], bf[4];
#pragma unroll
    for (int mi = 0; mi < 2; ++mi)
      af[mi] = *(const short8*)&As[buf][(wm + mi * 16 + fr) * 32 + fk];
#pragma unroll
    for (int ni = 0; ni < 4; ++ni)
      bf[ni] = *(const short8*)&Bs[buf][(wn + ni * 16 + fr) * 32 + fk];
    __builtin_amdgcn_s_setprio(1);
#pragma unroll
    for (int mi = 0; mi < 2; ++mi)
#pragma unroll
      for (int ni = 0; ni < 4; ++ni)
        acc[mi][ni] = __builtin_amdgcn_mfma_f32_16x16x32_bf16(
            af[mi], bf[ni], acc[mi][ni], 0, 0, 0);
    __builtin_amdgcn_s_setprio(0);
  }
#undef LOADT
#undef STORET

  const int er = (lane >> 4) * 4;
  const int ec = lane & 15;
#pragma unroll
  for (int mi = 0; mi < 2; ++mi) {
#pragma unroll
    for (int ni = 0; ni < 4; ++ni) {
      int gm = m0 + wm + mi * 16 + er;
      int gn = n0 + wn + ni * 16 + ec;
      float bv = bias[gn];
#pragma unroll
      for (int r = 0; r < 4; ++r)
        Cb[(size_t)(gm + r) * Nout + gn] = f2bf(acc[mi][ni][r] + bv);
    }
  }
}

// ---------------------------------------------- MFMA flash attention
// 1-D grid: all 16 heads of one (b, i0) share bid%8 -> same XCD, so the
// shared 128x512 code slice (and K/V) is fetched into that XCD's L2 once.
__global__ __launch_bounds__(256, 5) void attn_kernel(
    const unsigned short* __restrict__ qkv, const unsigned short* __restrict__ vtb,
    const unsigned char* __restrict__ code, const float* __restrict__ spatial_emb,
    const int* __restrict__ num_nodes, unsigned short* __restrict__ o)
{
  const int bid = blockIdx.x;
  const int xcd = bid & 7;
  const int inner = bid >> 3;       // 0..127
  const int h = inner & 15;
  const int g = (inner >> 4) * 8 + xcd;   // 0..63 = (b, i0-tile) group
  const int b = g >> 2;
  const int i0 = (g & 3) * 128;
  const int nn = num_nodes[b];
  if (i0 >= ((nn + 63) & ~63)) return;     // dead q-tile (64-granular)
  const int t  = threadIdx.x;
  const int lane = t & 63, w = t >> 6;
  const int q4 = lane >> 4, c = lane & 15;

  __shared__ __align__(16) unsigned short PB[4][32][72];  // 18.4 KB (bias->P; Qs overlay)
  __shared__ short8 Ks[64 * 4];
  __shared__ short8 Vt[32 * 8];
  __shared__ unsigned short sbx[16];

  short8* Qs = (short8*)&PB[0][0][0];

  if (t < 16)
    sbx[t] = (t < 12) ? f2bf(spatial_emb[t * H_ + h]) : (unsigned short)NEGBF;

  {
    int i = t >> 1, half = t & 1;
    const unsigned short* src =
        qkv + (size_t)(b * N_ + i0 + i) * QKV_LD + h * DH_ + half * 16;
    short8 v0 = *(const short8*)src;
    short8 v1 = *(const short8*)(src + 8);
    int sw = (i >> 2) & 3;
    Qs[i * 4 + ((half * 2) ^ sw)]     = v0;
    Qs[i * 4 + ((half * 2 + 1) ^ sw)] = v1;
  }
  __syncthreads();

  const int swz = (c >> 2) & 3;
  short8 Qf[2];
#pragma unroll
  for (int mt = 0; mt < 2; ++mt)
    Qf[mt] = Qs[(w * 32 + mt * 16 + c) * 4 + (q4 ^ swz)];

  short8 ones;
#pragma unroll
  for (int i = 0; i < 8; ++i) ones[i] = (short)ONEBF;

  f32x4 Oa[2][2], Osum[2];
#pragma unroll
  for (int mt = 0; mt < 2; ++mt) {
    Osum[mt] = (f32x4){0.f, 0.f, 0.f, 0.f};
#pragma unroll
    for (int dt = 0; dt < 2; ++dt) Oa[mt][dt] = (f32x4){0.f, 0.f, 0.f, 0.f};
  }

  const int jmax = min(N_, (nn + 63) & ~63);

  const int kj = t >> 2, kc = t & 3;
  const unsigned short* kbase =
      qkv + (size_t)(b * N_ + kj) * QKV_LD + 512 + h * DH_ + kc * 8;
  const int vd = t >> 3, vjc = t & 7;
  const unsigned short* vbase =
      vtb + ((size_t)(b * 512 + h * DH_ + vd)) * 512 + vjc * 8;
  const unsigned char* cbase = code + (size_t)(b * N_ + i0 + w * 32) * N_;
  const int lc4 = c * 4;

  short8 kreg, vreg;
  unsigned int dreg[8];
#define PREFETCH(J0)                                                         \
  {                                                                          \
    kreg = *(const short8*)(kbase + (size_t)(J0) * QKV_LD);                  \
    vreg = *(const short8*)(vbase + (J0));                                   \
    _Pragma("unroll")                                                        \
    for (int it = 0; it < 8; ++it)                                           \
      dreg[it] = *(const unsigned int*)(cbase + (size_t)(it * 4 + q4) * N_ + \
                                        (J0) + lc4);                         \
  }
  PREFETCH(0)

  for (int j0 = 0; j0 < jmax; j0 += 64) {
    __syncthreads();
    Ks[kj * 4 + (kc ^ ((kj >> 2) & 3))] = kreg;
    Vt[vd * 8 + (vjc ^ (vd & 7))] = vreg;
#pragma unroll
    for (int it = 0; it < 8; ++it) {
      unsigned int cw = dreg[it];
      unsigned int e0 = sbx[cw & 15], e1 = sbx[(cw >> 8) & 15];
      unsigned int e2 = sbx[(cw >> 16) & 15], e3 = sbx[cw >> 24];
      unsigned int* pw = (unsigned int*)&PB[w][it * 4 + q4][lc4];
      pw[0] = e0 | (e1 << 16);
      pw[1] = e2 | (e3 << 16);
    }
    __syncthreads();

    if (j0 + 64 < jmax) PREFETCH(j0 + 64)

    f32x4 S[2][4];
#pragma unroll
    for (int nt = 0; nt < 4; ++nt) {
      short8 Kf = Ks[(nt * 16 + c) * 4 + (q4 ^ swz)];
#pragma unroll
      for (int mt = 0; mt < 2; ++mt)
        S[mt][nt] = __builtin_amdgcn_mfma_f32_16x16x32_bf16(
            Qf[mt], Kf, (f32x4){0.f, 0.f, 0.f, 0.f}, 0, 0, 0);
    }

#pragma unroll
    for (int mt = 0; mt < 2; ++mt) {
#pragma unroll
      for (int r = 0; r < 4; ++r) {
        const int row = mt * 16 + q4 * 4 + r;
#pragma unroll
        for (int nt = 0; nt < 4; ++nt) {
          float p = __expf(fminf(S[mt][nt][r] + bf2f(PB[w][row][nt * 16 + c]), 60.f));
          PB[w][row][nt * 16 + c] = f2bf(p);
        }
      }
    }

#pragma unroll
    for (int js = 0; js < 2; ++js) {
      short8 Pa[2], Vf[2];
#pragma unroll
      for (int mt = 0; mt < 2; ++mt)
        Pa[mt] = *(const short8*)&PB[w][mt * 16 + c][js * 32 + q4 * 8];
#pragma unroll
      for (int dt = 0; dt < 2; ++dt) {
        const int d = dt * 16 + c;
        Vf[dt] = Vt[d * 8 + ((js * 4 + q4) ^ (d & 7))];
      }
#pragma unroll
      for (int mt = 0; mt < 2; ++mt) {
#pragma unroll
        for (int dt = 0; dt < 2; ++dt)
          Oa[mt][dt] = __builtin_amdgcn_mfma_f32_16x16x32_bf16(
              Pa[mt], Vf[dt], Oa[mt][dt], 0, 0, 0);
        Osum[mt] = __builtin_amdgcn_mfma_f32_16x16x32_bf16(
            Pa[mt], ones, Osum[mt], 0, 0, 0);
      }
    }
  }
#undef PREFETCH

#pragma unroll
  for (int mt = 0; mt < 2; ++mt)
#pragma unroll
    for (int r = 0; r < 4; ++r) {
      float inv = 1.f / Osum[mt][r];
      int i = i0 + w * 32 + mt * 16 + q4 * 4 + r;
      unsigned short* op = o + (size_t)(b * N_ + i) * F_ + h * DH_;
#pragma unroll
      for (int dt = 0; dt < 2; ++dt)
        op[dt * 16 + c] = f2bf(Oa[mt][dt][r] * inv);
    }
}

// ---------------------------------------------------------------- add + LN
// Wave-per-row: 64 lanes x 8 bf16 = 512 cols; shuffle-only reduce, no LDS,
// no __syncthreads. 4 rows per 256-thread block. xb = LN(xb + t) in place.
__global__ __launch_bounds__(256) void add_ln_kernel(
    unsigned short* __restrict__ xb, const unsigned short* __restrict__ t,
    const float* __restrict__ gam, const float* __restrict__ bet,
    const int* __restrict__ num_nodes)
{
  const int w = threadIdx.x >> 6, lane = threadIdx.x & 63;
  const int row = blockIdx.x * 4 + w;
  {
    int bb = row >> 9;
    int nnr = (num_nodes[bb] + 63) & ~63;
    if ((row & 511) >= nnr) return;   // wave-uniform
  }
  const int c0 = lane * 8;
  const size_t base = (size_t)row * F_ + c0;
  short8 xp = *(const short8*)(xb + base);
  short8 tp = *(const short8*)(t + base);
  float v[8];
#pragma unroll
  for (int j = 0; j < 8; ++j)
    v[j] = bf2f((unsigned short)xp[j]) + bf2f((unsigned short)tp[j]);
  float s = ((v[0] + v[1]) + (v[2] + v[3])) + ((v[4] + v[5]) + (v[6] + v[7]));
#pragma unroll
  for (int off = 32; off > 0; off >>= 1) s += __shfl_xor(s, off, 64);
  float mean = s * (1.f / 512.f);
  float e[8], ss = 0.f;
#pragma unroll
  for (int j = 0; j < 8; ++j) { e[j] = v[j] - mean; ss += e[j] * e[j]; }
#pragma unroll
  for (int off = 32; off > 0; off >>= 1) ss += __shfl_xor(ss, off, 64);
  float rstd = rsqrtf(ss * (1.f / 512.f) + 1e-5f);
  float4 g0 = *(const float4*)(gam + c0);
  float4 g1 = *(const float4*)(gam + c0 + 4);
  float4 b0 = *(const float4*)(bet + c0);
  float4 b1 = *(const float4*)(bet + c0 + 4);
  float g[8] = {g0.x, g0.y, g0.z, g0.w, g1.x, g1.y, g1.z, g1.w};
  float be[8] = {b0.x, b0.y, b0.z, b0.w, b1.x, b1.y, b1.z, b1.w};
  unsigned short o8[8];
#pragma unroll
  for (int j = 0; j < 8; ++j) o8[j] = f2bf(e[j] * rstd * g[j] + be[j]);
  *(short8*)(xb + base) = *(short8*)o8;
}

// ---------------------------------------------------------------- pool (2-stage, bf16 in)
__device__ __forceinline__ float block_reduce_sum(float val, float* sbuf) {
#pragma unroll
  for (int off = 32; off > 0; off >>= 1) val += __shfl_xor(val, off, 64);
  int wid = threadIdx.x >> 6;
  if ((threadIdx.x & 63) == 0) sbuf[wid] = val;
  __syncthreads();
  val = sbuf[0] + sbuf[1] + sbuf[2] + sbuf[3];
  __syncthreads();
  return val;
}

__global__ __launch_bounds__(256) void pool_partial_kernel(
    const unsigned short* __restrict__ xb, const int* __restrict__ num_nodes,
    const float* __restrict__ clf_w, float* __restrict__ part)
{
  __shared__ float sbuf[4];
  int b = blockIdx.x, s = blockIdx.y, t = threadIdx.x;
  int nn = num_nodes[b];
  const unsigned short* xp = xb + (size_t)b * N_ * F_;
  int c0 = t * 2;
  float w0 = clf_w[c0], w1 = clf_w[c0 + 1];
  float a = 0.f;
  for (int n = s; n < nn; n += 32) {
    unsigned int p = *(const unsigned int*)(xp + (size_t)n * F_ + c0);
    a += bf2f((unsigned short)(p & 0xffff)) * w0 + bf2f((unsigned short)(p >> 16)) * w1;
  }
  float tot = block_reduce_sum(a, sbuf);
  if (t == 0) part[b * 32 + s] = tot;
}

__global__ __launch_bounds__(64) void pool_final_kernel(
    const float* __restrict__ part, const int* __restrict__ num_nodes,
    const float* __restrict__ clf_b, float* __restrict__ out)
{
  int b = threadIdx.x;
  if (b >= B_) return;
  float tot = 0.f;
#pragma unroll
  for (int s = 0; s < 32; ++s) tot += part[b * 32 + s];
  float logit = tot / (float)num_nodes[b] + clf_b[0];
  out[b] = 1.f / (1.f + __expf(-logit));
}

// ---------------------------------------------------------------- launch
extern "C" void kernel_launch(void* const* d_in, const int* in_sizes, int n_in,
                              void* d_out, int out_size, void* d_ws, size_t ws_size,
                              hipStream_t stream)
{
  (void)in_sizes; (void)n_in; (void)out_size; (void)ws_size;

  const float* nfeats    = (const float*)d_in[0];
  const int*   degrees   = (const int*)d_in[1];
  const int*   dist_idx  = (const int*)d_in[2];
  const int*   num_nodes = (const int*)d_in[3];
  const float* deg_in    = (const float*)d_in[4];
  const float* deg_out   = (const float*)d_in[5];
  const float* semb      = (const float*)d_in[6];
  const float* Wq = (const float*)d_in[7];  const float* bq = (const float*)d_in[8];
  const float* Wk = (const float*)d_in[9];  const float* bk = (const float*)d_in[10];
  const float* Wv = (const float*)d_in[11]; const float* bv = (const float*)d_in[12];
  const float* Wo = (const float*)d_in[13]; const float* bo = (const float*)d_in[14];
  const float* ln1s = (const float*)d_in[15]; const float* ln1b = (const float*)d_in[16];
  const float* W1 = (const float*)d_in[17]; const float* b1 = (const float*)d_in[18];
  const float* W2 = (const float*)d_in[19]; const float* b2 = (const float*)d_in[20];
  const float* ln2s = (const float*)d_in[21]; const float* ln2b = (const float*)d_in[22];
  const float* clfw = (const float*)d_in[23]; const float* clfb = (const float*)d_in[24];
  float* out = (float*)d_out;

  const int M = B_ * N_;            // 8192
  char* p = (char*)d_ws;
  auto alloc = [&](size_t bytes) { char* r = p; p += (bytes + 255) & ~255ULL; return r; };

  unsigned short* xb    = (unsigned short*)alloc((size_t)M * F_ * 2);     // 8 MB
  char*           R     = alloc((size_t)M * QKV_LD * 4);                  // 50 MB
  unsigned short* ob    = (unsigned short*)alloc((size_t)M * F_ * 2);     // 8 MB
  unsigned short* vtb   = (unsigned short*)alloc((size_t)M * F_ * 2);     // 8 MB V^T
  unsigned short* wQKVt = (unsigned short*)alloc((size_t)L_ * QKV_LD * F_ * 2);
  unsigned short* wOt   = (unsigned short*)alloc((size_t)L_ * F_ * F_ * 2);
  unsigned short* wW1t  = (unsigned short*)alloc((size_t)L_ * HID_ * F_ * 2);
  unsigned short* wW2t  = (unsigned short*)alloc((size_t)L_ * F_ * HID_ * 2);
  float*          bqkv  = (float*)alloc((size_t)L_ * QKV_LD * 4);
  float*          part  = (float*)alloc((size_t)B_ * 32 * 4);
  unsigned char*  code  = (unsigned char*)alloc((size_t)B_ * N_ * N_);    // 4 MB

  unsigned short* qkvb = (unsigned short*)R;                 // bf16 [M][1536]
  unsigned short* tbh  = (unsigned short*)R;                 // bf16 [M][512] (reuse)
  unsigned short* hb   = (unsigned short*)(R + (size_t)M * F_ * 4);  // bf16 [M][2048]

  const float scale = 0.17677669529663687f;  // 1/sqrt(32)

  dim3 tb32(32, 8);
  tconv4_kernel<<<dim3(16, 16, 4 * L_), tb32, 0, stream>>>(
      Wq, Wk, Wv, Wo, wQKVt, wOt);
  tconv_kernel<<<dim3(64, 16, L_), tb32, 0, stream>>>(W1, wW1t, F_, HID_,
      (size_t)F_ * HID_, (size_t)F_ * HID_, 0);
  tconv_kernel<<<dim3(16, 64, L_), tb32, 0, stream>>>(W2, wW2t, HID_, F_,
      (size_t)F_ * HID_, (size_t)F_ * HID_, 0);
  biasqkv_kernel<<<dim3((L_ * QKV_LD + 255) / 256), 256, 0, stream>>>(bq, bk, bv, bqkv);
  packcode_kernel<<<dim3((B_ * N_ * N_) / 4 / 256), 256, 0, stream>>>(
      dist_idx, num_nodes, code);

  embed_kernel<<<dim3((M * F_) / 4 / 256), 256, 0, stream>>>(
      nfeats, degrees, num_nodes, deg_in, deg_out, xb);

  for (int l = 0; l < L_; ++l) {
    const unsigned short* wqkv_l = wQKVt + (size_t)l * QKV_LD * F_;
    const unsigned short* wo_l   = wOt   + (size_t)l * F_ * F_;
    const unsigned short* w1_l   = wW1t  + (size_t)l * HID_ * F_;
    const unsigned short* w2_l   = wW2t  + (size_t)l * F_ * HID_;

    // QKV: 64 row panels x 12 col tiles, 128-row tiles, XCD-grouped
    mfma_gemm_kernel<<<dim3(64 * 12), 256, 0, stream>>>(
        xb, wqkv_l, bqkv + l * QKV_LD, qkvb, vtb, F_, QKV_LD, 12, scale, 2, num_nodes);

    attn_kernel<<<dim3(1024), 256, 0, stream>>>(
        qkvb, vtb, code, semb, num_nodes, ob);

    // o-proj: 128 row panels x 4 col tiles (64-row tiles)
    mfma_gemm64_kernel<<<dim3(128 * 4), 256, 0, stream>>>(
        ob, wo_l, bo + l * F_, tbh, F_, F_, 4, num_nodes);
    add_ln_kernel<<<dim3(M / 4), 256, 0, stream>>>(
        xb, tbh, ln1s + l * F_, ln1b + l * F_, num_nodes);

    // FFN1: 64 row panels x 16 col tiles (128-row tiles)
    mfma_gemm_kernel<<<dim3(64 * 16), 256, 0, stream>>>(
        xb, w1_l, b1 + l * HID_, hb, nullptr, F_, HID_, 16, 1.f, 1, num_nodes);
    // FFN2: 128 row panels x 4 col tiles (64-row tiles), K=2048
    mfma_gemm64_kernel<<<dim3(128 * 4), 256, 0, stream>>>(
        hb, w2_l, b2 + l * F_, tbh, HID_, F_, 4, num_nodes);
    add_ln_kernel<<<dim3(M / 4), 256, 0, stream>>>(
        xb, tbh, ln2s + l * F_, ln2b + l * F_, num_nodes);
  }

  pool_partial_kernel<<<dim3(B_, 32), 256, 0, stream>>>(xb, num_nodes, clfw, part);
  pool_final_kernel<<<dim3(1), 64, 0, stream>>>(part, num_nodes, clfb, out);
}